// Round 7
// baseline (501.936 us; speedup 1.0000x reference)
//
#include <hip/hip_runtime.h>
#include <math.h>

// Problem constants
#define TOK   4096    // B*N
#define EDIM  512
#define HEADS 8
#define DHEAD 64
#define GCOLS 32768   // H*D*D

typedef unsigned short u16;
typedef _Float16 f16;
typedef __attribute__((ext_vector_type(8))) f16 f16x8;      // 8 fp16 = 4 VGPRs (MFMA A/B frag)
typedef __attribute__((ext_vector_type(4))) f16 f16x4;
typedef __attribute__((ext_vector_type(4))) float f32x4;    // MFMA C/D frag
typedef __attribute__((ext_vector_type(4))) unsigned short u16x4;
typedef __attribute__((ext_vector_type(8))) unsigned short u16x8;

typedef const __attribute__((address_space(1))) void* gas_ptr;
typedef __attribute__((address_space(3))) void* las_ptr;

__device__ __forceinline__ void gll16(const void* g, void* lds) {
  // async global->LDS, 16B/lane: per-lane global addr, wave-uniform LDS base,
  // lane i lands at lds + i*16
  __builtin_amdgcn_global_load_lds((gas_ptr)g, (las_ptr)lds, 16, 0, 0);
}

__device__ __forceinline__ u16 f2h_bits(float f) {
  union { f16 h; u16 u; } v; v.h = (f16)f;   // RNE
  return v.u;
}

// Abramowitz-Stegun 7.1.26 erf: |abs err| <= 1.5e-7, ~15 VALU insts
__device__ __forceinline__ float fast_gelu(float x) {
  float s = x * 0.7071067811865475f;
  float ax = fabsf(s);
  float t = 1.0f / (1.0f + 0.3275911f * ax);
  float poly = t * (0.254829592f + t * (-0.284496736f + t * (1.421413741f +
               t * (-1.453152027f + t * 1.061405429f))));
  float e = __expf(-ax * ax);
  float r = 1.0f - poly * e;
  float erfv = copysignf(r, s);
  return 0.5f * x * (1.0f + erfv);
}

// ---------------------------------------------------------------- cast x -> fp16
__global__ void cast_f16_k(const float* __restrict__ in, u16* __restrict__ out, int n) {
  int i = (blockIdx.x * blockDim.x + threadIdx.x) * 4;
  if (i + 3 < n) {
    float4 f = *(const float4*)(in + i);
    u16x4 h;
    h.x = f2h_bits(f.x); h.y = f2h_bits(f.y);
    h.z = f2h_bits(f.z); h.w = f2h_bits(f.w);
    *(u16x4*)(out + i) = h;
  }
}

// -------------------- transpose W[K][N] -> Wt[N][K] fp16, 64x64 tile, u16x8 stores
__global__ void transpose_f16_k(const float* __restrict__ in, u16* __restrict__ out,
                                int K, int N) {
  __shared__ u16 tileT[64][72];   // [n_local][k_local], row 144B (16B-aligned)
  const int n0 = blockIdx.x * 64, k0 = blockIdx.y * 64;
  const int tid = threadIdx.x;    // 256
  const int kl = tid >> 4;        // 0..15
  const int nl4 = (tid & 15) * 4; // 0..60
  #pragma unroll
  for (int i = 0; i < 4; i++) {
    int k = kl + i * 16;
    float4 f = *(const float4*)(in + (size_t)(k0 + k) * N + n0 + nl4);
    tileT[nl4 + 0][k] = f2h_bits(f.x);
    tileT[nl4 + 1][k] = f2h_bits(f.y);
    tileT[nl4 + 2][k] = f2h_bits(f.z);
    tileT[nl4 + 3][k] = f2h_bits(f.w);
  }
  __syncthreads();
  const int nr = tid >> 3;         // 0..31
  const int ks = (tid & 7) * 8;    // 0..56
  #pragma unroll
  for (int p = 0; p < 2; p++) {
    int n = nr + p * 32;
    u16x8 v = *(const u16x8*)&tileT[n][ks];             // 16B LDS read
    *(u16x8*)(out + (size_t)(n0 + n) * K + k0 + ks) = v; // 16B global store
  }
}

// ---------------------------------------------------------------- QKV GEMM
// 128x128 tile, BK=64, 4 waves, fp16 MFMA, DOUBLE-BUFFERED staging:
// stage(s+1) issued before compute(s); one barrier per stage.
// q fp16 [B][H][N][D]; k fp16 [B][H][N][D]; v transposed fp16 [B][H][D][N].
__global__ __launch_bounds__(256, 2) void qkv_gemm_k(
    const u16* __restrict__ xf, const u16* __restrict__ Wqt,
    const u16* __restrict__ Wkt, const u16* __restrict__ Wvt,
    const float* __restrict__ bq, const float* __restrict__ bk, const float* __restrict__ bv,
    u16* __restrict__ qho, u16* __restrict__ ko, u16* __restrict__ vTo) {
  __shared__ __align__(16) u16 As[2][16 * 512];   // 2x16KB
  __shared__ __align__(16) u16 Bs[2][16 * 512];   // 2x16KB
  const int which = blockIdx.z;
  const u16* Wt = which == 0 ? Wqt : (which == 1 ? Wkt : Wvt);
  const float* bias = which == 0 ? bq : (which == 1 ? bk : bv);
  const int m0 = blockIdx.x * 128;
  const int n0 = blockIdx.y * 128;
  const int tid = threadIdx.x;
  const int w = tid >> 6, lane = tid & 63, l15 = lane & 15, quad = lane >> 4;
  const int mhalf = w >> 1, nhalf = w & 1;

  auto stage = [&](int s) {
    int kk = s * 64, buf = s & 1;
    #pragma unroll
    for (int i = 0; i < 8; i++) {
      int cb = w * 8 + i;
      if (cb < 16) {
        int ks = cb >> 3, mt = cb & 7;
        gll16(xf + (size_t)(m0 + mt * 16 + l15) * 512 + kk + ks * 32 + quad * 8,
              &As[buf][cb * 512]);
      } else {
        int bi = cb - 16, ks = bi >> 3, nt = bi & 7;
        gll16(Wt + (size_t)(n0 + nt * 16 + l15) * 512 + kk + ks * 32 + quad * 8,
              &Bs[buf][bi * 512]);
      }
    }
  };

  f32x4 acc[4][4];
  #pragma unroll
  for (int i = 0; i < 4; i++)
    #pragma unroll
    for (int j = 0; j < 4; j++) acc[i][j] = f32x4{0.f, 0.f, 0.f, 0.f};

  stage(0);
  __syncthreads();
  for (int s = 0; s < 8; s++) {
    if (s < 7) stage(s + 1);
    int buf = s & 1;
    #pragma unroll
    for (int ks = 0; ks < 2; ks++) {
      f16x8 a[4], b[4];
      #pragma unroll
      for (int mt = 0; mt < 4; mt++)
        a[mt] = *(const f16x8*)(&As[buf][(ks * 8 + mhalf * 4 + mt) * 512 + lane * 8]);
      #pragma unroll
      for (int nt = 0; nt < 4; nt++)
        b[nt] = *(const f16x8*)(&Bs[buf][(ks * 8 + nhalf * 4 + nt) * 512 + lane * 8]);
      #pragma unroll
      for (int mt = 0; mt < 4; mt++)
        #pragma unroll
        for (int nt = 0; nt < 4; nt++)
          acc[mt][nt] = __builtin_amdgcn_mfma_f32_16x16x32_f16(a[mt], b[nt], acc[mt][nt], 0, 0, 0);
    }
    __syncthreads();
  }
  #pragma unroll
  for (int nt = 0; nt < 4; nt++) {
    int col = n0 + (nhalf * 4 + nt) * 16 + l15;
    float bia = bias[col];
    int h = col >> 6, d = col & 63;
    #pragma unroll
    for (int mt = 0; mt < 4; mt++) {
      #pragma unroll
      for (int r = 0; r < 4; r++) {
        int t = m0 + (mhalf * 4 + mt) * 16 + quad * 4 + r;
        int b_ = t >> 10, n = t & 1023;
        float val = acc[mt][nt][r] + bia;
        size_t idx = (((size_t)(b_ * 8 + h) * 1024) + n) * 64 + d;
        if (which == 0)      qho[idx] = f2h_bits(val);
        else if (which == 1) ko[idx] = f2h_bits(val);
        else                 vTo[(((size_t)(b_ * 8 + h) * 64) + d) * 1024 + n] = f2h_bits(val);
      }
    }
  }
}

// ---------------------------------------------------------------- fused g-GEMM + q.g
// Block = 128 tokens x one head x half the d-range, 512 threads (8 waves).
// DOUBLE-BUFFERED As/Bs (112KB LDS, 1 block/CU): stage(s+1) issued before
// compute(s); ONE barrier per stage. 64 stages = 8 jp x 8 kk.
// Partial stride = TOK*EDIM elems (full [B][H][N][D] tensor).
__global__ __launch_bounds__(512, 2) void qg_fused_k(
    const u16* __restrict__ xf, const u16* __restrict__ Wgt,
    const float* __restrict__ bg, const u16* __restrict__ qh,
    float* __restrict__ qgp) {
  __shared__ __align__(16) u16 As[2][16 * 512];  // 2x16KB: 128 tok x 64 K
  __shared__ __align__(16) u16 Bs[2][32 * 512];  // 2x32KB: 256 cols x 64 K
  __shared__ __align__(16) u16 Qs[128 * 64];     // 16KB: q fp16 rows
  const int head = blockIdx.x & 7;             // XCD-pinned per head
  const int jh = (blockIdx.x >> 3) & 1;        // which half of the d-range
  const int t0 = (blockIdx.x >> 4) * 128;
  const int tid = threadIdx.x;
  const int w = tid >> 6, lane = tid & 63, l15 = lane & 15, quad = lane >> 4;
  const int mhalf = w >> 2;   // 0..1  (token half)
  const int ntA = w & 3;      // 0..3  (e-range /16)
  const int b_ = t0 >> 10, nseq0 = t0 & 1023;
  const u16* qbase = qh + (((size_t)(b_ * 8 + head) * 1024) + nseq0) * 64;

  auto stage = [&](int s) {
    int jp = s >> 3, kk = (s & 7) * 64, buf = s & 1;
    int c0s = head * 4096 + (jh * 16 + jp * 2) * 128;
    #pragma unroll
    for (int i = 0; i < 6; i++) {
      int cb = w * 6 + i;
      if (cb < 16) {
        int ks = cb >> 3, mt = cb & 7;
        gll16(xf + (size_t)(t0 + mt * 16 + l15) * 512 + kk + ks * 32 + quad * 8,
              &As[buf][cb * 512]);
      } else {
        int bi = cb - 16, ks = bi >> 4, nt = bi & 15;
        gll16(Wgt + (size_t)(c0s + nt * 16 + l15) * 512 + kk + ks * 32 + quad * 8,
              &Bs[buf][bi * 512]);
      }
    }
  };

  // stage Qs (contiguous 16KB fp16) + first tile
  #pragma unroll
  for (int i = 0; i < 2; i++) {
    int cb = w * 2 + i;
    gll16(qbase + (size_t)cb * 512 + (size_t)lane * 8, Qs + (size_t)cb * 512);
  }
  stage(0);

  f32x4 qg[4];
  #pragma unroll
  for (int i = 0; i < 4; i++) qg[i] = f32x4{0.f, 0.f, 0.f, 0.f};
  f32x4 zacc[4][4];   // [mt][z]: z = j0d0,j0d1,j1d0,j1d1
  #pragma unroll
  for (int i = 0; i < 4; i++)
    #pragma unroll
    for (int z = 0; z < 4; z++) zacc[i][z] = f32x4{0.f, 0.f, 0.f, 0.f};

  __syncthreads();

  for (int s = 0; s < 64; s++) {
    if (s < 63) stage(s + 1);    // loads fly during compute + epilogue
    const int buf = s & 1;
    #pragma unroll
    for (int ks = 0; ks < 2; ks++) {
      f16x8 a[4];
      #pragma unroll
      for (int mt = 0; mt < 4; mt++)
        a[mt] = *(const f16x8*)(&As[buf][(ks * 8 + mhalf * 4 + mt) * 512 + lane * 8]);
      #pragma unroll
      for (int z = 0; z < 4; z++) {
        int nt = (z >> 1) * 8 + (z & 1) * 4 + ntA;
        f16x8 b = *(const f16x8*)(&Bs[buf][(ks * 16 + nt) * 512 + lane * 8]);
        #pragma unroll
        for (int mt = 0; mt < 4; mt++)
          zacc[mt][z] = __builtin_amdgcn_mfma_f32_16x16x32_f16(a[mt], b, zacc[mt][z], 0, 0, 0);
      }
    }
    if ((s & 7) == 7) {
      // epilogue for jp = s>>3: bias + fast gelu + contract with fp16 q
      const int jp = s >> 3;
      const int j0 = jh * 16 + jp * 2;
      const int c0 = head * 4096 + j0 * 128;
      float bgv[4];
      #pragma unroll
      for (int z = 0; z < 4; z++) {
        int nt = (z >> 1) * 8 + (z & 1) * 4 + ntA;
        bgv[z] = bg[c0 + nt * 16 + l15];
      }
      const int d0 = 2 * j0;
      #pragma unroll
      for (int mt = 0; mt < 4; mt++) {
        #pragma unroll
        for (int r = 0; r < 4; r++) {
          int row = mhalf * 64 + mt * 16 + quad * 4 + r;
          f16x4 qp = *(const f16x4*)(Qs + row * 64 + d0);  // q[row][2j0..2j0+3]
          float g0 = fast_gelu(zacc[mt][0][r] + bgv[0]);
          float g1 = fast_gelu(zacc[mt][1][r] + bgv[1]);
          float g2 = fast_gelu(zacc[mt][2][r] + bgv[2]);
          float g3 = fast_gelu(zacc[mt][3][r] + bgv[3]);
          qg[mt][r] += (float)qp.x * g0 + (float)qp.y * g1 +
                       (float)qp.z * g2 + (float)qp.w * g3;
          zacc[mt][0][r] = 0.f; zacc[mt][1][r] = 0.f;
          zacc[mt][2][r] = 0.f; zacc[mt][3][r] = 0.f;
        }
      }
    }
    __syncthreads();
  }
  float* qout = qgp + (size_t)jh * TOK * EDIM;   // partial stride = 2M elems
  const int eb = ntA * 16;
  #pragma unroll
  for (int mt = 0; mt < 4; mt++) {
    #pragma unroll
    for (int r = 0; r < 4; r++) {
      int t = t0 + mhalf * 64 + mt * 16 + quad * 4 + r;
      int bb = t >> 10, n = t & 1023;
      qout[(((size_t)(bb * 8 + head) * 1024) + n) * 64 + eb + l15] = qg[mt][r];
    }
  }
}

// ---------------------------------------------------------------- flash attention
// Block = (b,h,qtile64), 4 waves x 16 q-rows. qg = partial0+partial1 (fp32->fp16),
// S = qg@k^T fp16 MFMA, online softmax, P->LDS (C->A layout turn), O += P@V.
__global__ __launch_bounds__(256, 2) void attn_k(
    const float* __restrict__ qgp, const u16* __restrict__ kb,
    const u16* __restrict__ vTb, float* __restrict__ out) {
  __shared__ __align__(16) u16 Ks[8 * 512];
  __shared__ __align__(16) u16 Vs[8 * 512];
  __shared__ __align__(16) f16 Ps[4][16 * 72];    // per-wave P, row stride 72
  const int idx = blockIdx.x;
  const int bh = idx & 31;   // b*8+h -> XCD = bh%8
  const int qt = idx >> 5;
  const int b_ = bh >> 3, h = bh & 7;
  const int tid = threadIdx.x;
  const int w = tid >> 6, lane = tid & 63, l15 = lane & 15, quad = lane >> 4;

  const float* qg0 = qgp + (size_t)bh * 1024 * 64;
  const float* qg1 = qg0 + (size_t)TOK * EDIM;   // partial stride = 2M elems
  const u16* kB  = kb  + (size_t)bh * 1024 * 64;
  const u16* vB  = vTb + (size_t)bh * 64 * 1024;

  f16x8 aq[2];
  #pragma unroll
  for (int ks = 0; ks < 2; ks++) {
    size_t off = (size_t)(qt * 64 + w * 16 + l15) * 64 + ks * 32 + quad * 8;
    f16x8 v;
    #pragma unroll
    for (int e = 0; e < 8; e++)
      v[e] = (f16)(qg0[off + e] + qg1[off + e]);
    aq[ks] = v;
  }

  f32x4 o[4];
  #pragma unroll
  for (int i = 0; i < 4; i++) o[i] = f32x4{0.f, 0.f, 0.f, 0.f};
  float m_old[4], l_old[4];
  #pragma unroll
  for (int r = 0; r < 4; r++) { m_old[r] = -1e30f; l_old[r] = 0.f; }

  for (int kt = 0; kt < 16; kt++) {
    #pragma unroll
    for (int i = 0; i < 2; i++) {
      int cb = w * 2 + i;
      int ks = cb >> 2, nt = cb & 3;
      gll16(kB + (size_t)(kt * 64 + nt * 16 + l15) * 64 + ks * 32 + quad * 8, Ks + cb * 512);
      gll16(vB + (size_t)(nt * 16 + l15) * 1024 + kt * 64 + ks * 32 + quad * 8, Vs + cb * 512);
    }
    __syncthreads();
    f32x4 s[4];
    #pragma unroll
    for (int nt = 0; nt < 4; nt++) s[nt] = f32x4{0.f, 0.f, 0.f, 0.f};
    #pragma unroll
    for (int ks = 0; ks < 2; ks++)
      #pragma unroll
      for (int nt = 0; nt < 4; nt++) {
        f16x8 kf = *(const f16x8*)(Ks + (ks * 4 + nt) * 512 + lane * 8);
        s[nt] = __builtin_amdgcn_mfma_f32_16x16x32_f16(aq[ks], kf, s[nt], 0, 0, 0);
      }
    float rmax[4];
    #pragma unroll
    for (int r = 0; r < 4; r++)
      rmax[r] = fmaxf(fmaxf(s[0][r], s[1][r]), fmaxf(s[2][r], s[3][r]));
    #pragma unroll
    for (int off = 1; off < 16; off <<= 1)
      #pragma unroll
      for (int r = 0; r < 4; r++)
        rmax[r] = fmaxf(rmax[r], __shfl_xor(rmax[r], off));
    float alpha[4], rsum[4];
    #pragma unroll
    for (int r = 0; r < 4; r++) {
      float mn = fmaxf(m_old[r], rmax[r]);
      alpha[r] = __expf(m_old[r] - mn);
      m_old[r] = mn;
      rsum[r] = 0.f;
    }
    #pragma unroll
    for (int nt = 0; nt < 4; nt++)
      #pragma unroll
      for (int r = 0; r < 4; r++) {
        float p = __expf(s[nt][r] - m_old[r]);
        rsum[r] += p;
        Ps[w][(quad * 4 + r) * 72 + nt * 16 + l15] = (f16)p;
      }
    #pragma unroll
    for (int off = 1; off < 16; off <<= 1)
      #pragma unroll
      for (int r = 0; r < 4; r++)
        rsum[r] += __shfl_xor(rsum[r], off);
    #pragma unroll
    for (int r = 0; r < 4; r++) l_old[r] = l_old[r] * alpha[r] + rsum[r];
    #pragma unroll
    for (int nt = 0; nt < 4; nt++)
      #pragma unroll
      for (int r = 0; r < 4; r++) o[nt][r] *= alpha[r];
    #pragma unroll
    for (int ks = 0; ks < 2; ks++) {
      f16x8 pa = *(const f16x8*)(&Ps[w][l15 * 72 + ks * 32 + quad * 8]);
      #pragma unroll
      for (int nt = 0; nt < 4; nt++) {
        f16x8 vf = *(const f16x8*)(Vs + (ks * 4 + nt) * 512 + lane * 8);
        o[nt] = __builtin_amdgcn_mfma_f32_16x16x32_f16(pa, vf, o[nt], 0, 0, 0);
      }
    }
    __syncthreads();
  }
  #pragma unroll
  for (int r = 0; r < 4; r++) {
    float inv = 1.f / l_old[r];
    int n = qt * 64 + w * 16 + quad * 4 + r;
    #pragma unroll
    for (int nt = 0; nt < 4; nt++)
      out[((size_t)(b_ * 1024 + n)) * 512 + h * 64 + nt * 16 + l15] = o[nt][r] * inv;
  }
}

// ----------------------------------------------------------------------- host
extern "C" void kernel_launch(void* const* d_in, const int* in_sizes, int n_in,
                              void* d_out, int out_size, void* d_ws, size_t ws_size,
                              hipStream_t stream) {
  const float* x  = (const float*)d_in[0];
  const float* Wq = (const float*)d_in[1];
  const float* bq = (const float*)d_in[2];
  const float* Wk = (const float*)d_in[3];
  const float* bk = (const float*)d_in[4];
  const float* Wv = (const float*)d_in[5];
  const float* bv = (const float*)d_in[6];
  const float* Wg = (const float*)d_in[7];
  const float* bg = (const float*)d_in[8];
  float* out = (float*)d_out;

  const size_t NX = (size_t)TOK * EDIM;        // 2M elems
  const size_t NWG = (size_t)GCOLS * EDIM;     // 16.8M elems
  const size_t NW = (size_t)EDIM * EDIM;       // 256K elems

  char* p = (char*)d_ws;
  u16* xf  = (u16*)p; p += NX * 2;             // x fp16
  u16* Wgt = (u16*)p; p += NWG * 2;            // Wg^T fp16 (33.5 MB)
  u16* Wqt = (u16*)p; p += NW * 2;
  u16* Wkt = (u16*)p; p += NW * 2;
  u16* Wvt = (u16*)p; p += NW * 2;
  u16* qh  = (u16*)p; p += NX * 2;             // q fp16 [B][H][N][D]
  u16* kf  = (u16*)p; p += NX * 2;             // k fp16
  u16* vT  = (u16*)p; p += NX * 2;             // v^T fp16
  float* qgp = (float*)p; p += NX * 4 * 2;     // qg fp32 partials [2][B][H][N][D]

  hipLaunchKernelGGL(cast_f16_k, dim3(NX / 1024), dim3(256), 0, stream,
                     x, xf, (int)NX);
  hipLaunchKernelGGL(transpose_f16_k, dim3(EDIM / 64, EDIM / 64), dim3(256), 0, stream,
                     Wq, Wqt, EDIM, EDIM);
  hipLaunchKernelGGL(transpose_f16_k, dim3(EDIM / 64, EDIM / 64), dim3(256), 0, stream,
                     Wk, Wkt, EDIM, EDIM);
  hipLaunchKernelGGL(transpose_f16_k, dim3(EDIM / 64, EDIM / 64), dim3(256), 0, stream,
                     Wv, Wvt, EDIM, EDIM);
  hipLaunchKernelGGL(transpose_f16_k, dim3(GCOLS / 64, EDIM / 64), dim3(256), 0, stream,
                     Wg, Wgt, EDIM, GCOLS);
  hipLaunchKernelGGL(qkv_gemm_k, dim3(TOK / 128, EDIM / 128, 3), dim3(256), 0, stream,
                     xf, Wqt, Wkt, Wvt, bq, bk, bv, qh, kf, vT);
  hipLaunchKernelGGL(qg_fused_k, dim3(512), dim3(512), 0, stream,
                     xf, Wgt, bg, qh, qgp);
  hipLaunchKernelGGL(attn_k, dim3(512), dim3(256), 0, stream,
                     qgp, kf, vT, out);
}